// Round 2
// baseline (232.303 us; speedup 1.0000x reference)
//
#include <hip/hip_runtime.h>

// Haar DWT, mode=0 (no pad).
// in : (2,16,16,256,256) f32  -> flat plane index pl = b*256 + c*16 + d in [0,512), each plane 256x256
// out: (2,64,16,128,128) f32  -> flat (b*1024 + s*256 + pcd)*16384 + h2*128 + w2
//
// Per 2x2 input quad (a=even/even, b=odd/even, c=even/odd, d=odd/odd), all *0.5:
//   LL = a+b+c+d ; HL = -a-b+c+d ; LH = -a+b-c+d ; HH = a-b-c+d
//
// Thread layout: idx = (plane[9b], h2[7b], w2p[6b]); w2p indexes PAIRS of output cols.
//   loads : float4 @ (2h2, 4*w2p) and (2h2+1, 4*w2p)   -> 16 B/lane, coalesced
//   stores: float2 per subband                          -> 8 B/lane x4, coalesced
__global__ __launch_bounds__(256) void dwt_haar_fwd(const float* __restrict__ in,
                                                    float* __restrict__ out) {
    const int idx  = blockIdx.x * 256 + threadIdx.x;   // 0 .. 4,194,304
    const int w2p  = idx & 63;          // output-col pair, 64 pairs per 128-wide row
    const int t    = idx >> 6;
    const int h2   = t & 127;           // output row
    const int pl   = t >> 7;            // input plane 0..511
    const int b    = pl >> 8;           // batch
    const int pcd  = pl & 255;          // c*16+d

    const float* rbase = in + pl * 65536 + (h2 << 1) * 256 + (w2p << 2);
    const float4 r0 = *(const float4*)(rbase);         // row 2h2   : a_a c_a a_b c_b
    const float4 r1 = *(const float4*)(rbase + 256);   // row 2h2+1 : b_a d_a b_b d_b

    // pair a (w2 = 2*w2p)
    const float se_a = r0.x + r1.x;    // a+b
    const float so_a = r0.y + r1.y;    // c+d
    const float de_a = r0.x - r1.x;    // a-b
    const float do_a = r0.y - r1.y;    // c-d
    // pair b (w2 = 2*w2p+1)
    const float se_b = r0.z + r1.z;
    const float so_b = r0.w + r1.w;
    const float de_b = r0.z - r1.z;
    const float do_b = r0.w - r1.w;

    const float2 LL = {  0.5f * (se_a + so_a),  0.5f * (se_b + so_b) };   //  a+b+c+d
    const float2 HL = {  0.5f * (so_a - se_a),  0.5f * (so_b - se_b) };   // -a-b+c+d
    const float2 LH = { -0.5f * (de_a + do_a), -0.5f * (de_b + do_b) };   // -a+b-c+d
    const float2 HH = {  0.5f * (de_a - do_a),  0.5f * (de_b - do_b) };   //  a-b-c+d

    float* obase = out + (size_t)(b * 1024 + pcd) * 16384 + (h2 << 7) + (w2p << 1);
    *(float2*)(obase            ) = LL;   // s=0
    *(float2*)(obase + 4194304  ) = HL;   // s=1: +256*16384
    *(float2*)(obase + 8388608  ) = LH;   // s=2
    *(float2*)(obase + 12582912 ) = HH;   // s=3
}

extern "C" void kernel_launch(void* const* d_in, const int* in_sizes, int n_in,
                              void* d_out, int out_size, void* d_ws, size_t ws_size,
                              hipStream_t stream) {
    const float* x = (const float*)d_in[0];
    float* out = (float*)d_out;
    // total threads = 512 planes * 128 rows * 64 col-pairs = 4,194,304
    dwt_haar_fwd<<<16384, 256, 0, stream>>>(x, out);
}

// Round 4
// 223.251 us; speedup vs baseline: 1.0405x; 1.0405x over previous
//
#include <hip/hip_runtime.h>

// Haar DWT, mode=0 (no pad).
// in : (2,16,16,256,256) f32  -> plane pl = b*256 + pcd in [0,512), each plane 256x256
// out: (2,64,16,128,128) f32  -> flat (b*1024 + s*256 + pcd)*16384 + h2*128 + w2
//
// Per 2x2 quad (a=ev/ev, b=od/ev, c=ev/od, d=od/od), all *0.5:
//   LL = a+b+c+d ; HL = -a-b+c+d ; LH = -a+b-c+d ; HH = a-b-c+d
//
// Thread layout: idx = (plane[9b], h2[7b], w4[5b]); w4 indexes groups of 4 output cols.
//   loads : 2x 16B per input row (rows 2h2, 2h2+1) -> contiguous 32 B/thread/row
//   stores: 1x 16B per subband                     -> 16 B/lane, fully coalesced
// Nontemporal on both sides: pure streaming, zero reuse -> don't churn L2.

typedef float v4f __attribute__((ext_vector_type(4)));  // native vector: OK for nontemporal builtins

__global__ __launch_bounds__(256) void dwt_haar_fwd(const float* __restrict__ in,
                                                    float* __restrict__ out) {
    const int idx = blockIdx.x * 256 + threadIdx.x;   // 0 .. 2,097,152
    const int w4  = idx & 31;           // group of 4 output cols (32 per 128-wide row)
    const int t   = idx >> 5;
    const int h2  = t & 127;            // output row
    const int pl  = t >> 7;             // input plane 0..511
    const int b   = pl >> 8;            // batch
    const int pcd = pl & 255;           // c*16+d

    const float* rbase = in + pl * 65536 + (h2 << 1) * 256 + (w4 << 3);
    const v4f* p0 = (const v4f*)rbase;           // row 2h2
    const v4f* p1 = (const v4f*)(rbase + 256);   // row 2h2+1
    const v4f r0a = __builtin_nontemporal_load(p0);     // a0 c0 a1 c1
    const v4f r0b = __builtin_nontemporal_load(p0 + 1); // a2 c2 a3 c3
    const v4f r1a = __builtin_nontemporal_load(p1);     // b0 d0 b1 d1
    const v4f r1b = __builtin_nontemporal_load(p1 + 1); // b2 d2 b3 d3

    // sums/diffs: s_e=a+b, s_o=c+d, d_e=a-b, d_o=c-d for 4 output columns
    const v4f s0 = r0a + r1a;   // se0 so0 se1 so1
    const v4f s1 = r0b + r1b;   // se2 so2 se3 so3
    const v4f d0 = r0a - r1a;   // de0 do0 de1 do1
    const v4f d1 = r0b - r1b;   // de2 do2 de3 do3

    const v4f LL = {  0.5f * (s0.x + s0.y),  0.5f * (s0.z + s0.w),  0.5f * (s1.x + s1.y),  0.5f * (s1.z + s1.w) };
    const v4f HL = {  0.5f * (s0.y - s0.x),  0.5f * (s0.w - s0.z),  0.5f * (s1.y - s1.x),  0.5f * (s1.w - s1.z) };
    const v4f LH = { -0.5f * (d0.x + d0.y), -0.5f * (d0.z + d0.w), -0.5f * (d1.x + d1.y), -0.5f * (d1.z + d1.w) };
    const v4f HH = {  0.5f * (d0.x - d0.y),  0.5f * (d0.z - d0.w),  0.5f * (d1.x - d1.y),  0.5f * (d1.z - d1.w) };

    float* obase = out + (size_t)(b * 1024 + pcd) * 16384 + (h2 << 7) + (w4 << 2);
    __builtin_nontemporal_store(LL, (v4f*)(obase           ));  // s=0
    __builtin_nontemporal_store(HL, (v4f*)(obase + 4194304 ));  // s=1: +256*16384
    __builtin_nontemporal_store(LH, (v4f*)(obase + 8388608 ));  // s=2
    __builtin_nontemporal_store(HH, (v4f*)(obase + 12582912));  // s=3
}

extern "C" void kernel_launch(void* const* d_in, const int* in_sizes, int n_in,
                              void* d_out, int out_size, void* d_ws, size_t ws_size,
                              hipStream_t stream) {
    const float* x = (const float*)d_in[0];
    float* out = (float*)d_out;
    // total threads = 512 planes * 128 rows * 32 col-quads = 2,097,152
    dwt_haar_fwd<<<8192, 256, 0, stream>>>(x, out);
}